// Round 1
// baseline (374.588 us; speedup 1.0000x reference)
//
#include <hip/hip_runtime.h>
#include <cmath>

#define NN 512

__device__ __forceinline__ int is_inf_f(float x) {
    return (__float_as_uint(x) & 0x7fffffffu) == 0x7f800000u;
}

// e = ef[1:4] = sqrt(3) * u[[1,2,0]] with the reference's exact epsilon fudges
__device__ __forceinline__ void edge_vec(float ci0, float ci1, float ci2,
                                         float cj0, float cj1, float cj2,
                                         float& e0, float& e1, float& e2) {
    float d0 = ci0 - cj0, d1 = ci1 - cj1, d2 = ci2 - cj2;
    float den = sqrtf(d0*d0 + d1*d1 + d2*d2 + 1e-12f) + 1e-5f;
    float r = 1.0f / den;
    d0 *= r; d1 *= r; d2 *= r;
    float n = sqrtf(d0*d0 + d1*d1 + d2*d2 + 1e-12f);
    float s = 1.7320508075688772f / n;
    e0 = d1 * s;  // sqrt3*u_y
    e1 = d2 * s;  // sqrt3*u_z
    e2 = d0 * s;  // sqrt3*u_x
}

// K1: block = (b, i). Transpose attn_disp -> ad (inf->0), edge_features,
// normalizer row counts, attn_mask + coords passthrough.
__global__ __launch_bounds__(256) void k_stage(
    const float* __restrict__ disp, const float* __restrict__ mask,
    const float* __restrict__ coords,
    float* __restrict__ ad_out, float* __restrict__ mask_out,
    float* __restrict__ coords_out, float* __restrict__ ef_out,
    float* __restrict__ ws_norm)
{
    const int blk = blockIdx.x;            // 2048 = B*N
    const int b = blk >> 9, i = blk & 511;
    const int tid = threadIdx.x;
    const float ci0 = coords[(b*NN+i)*3+0];
    const float ci1 = coords[(b*NN+i)*3+1];
    const float ci2 = coords[(b*NN+i)*3+2];
    int cnt = 0;
    #pragma unroll
    for (int r = 0; r < 2; r++) {
        const int j = r*256 + tid;
        float v[16];
        #pragma unroll
        for (int h = 0; h < 16; h++) {
            float x = disp[((b*16+h)*NN + i)*NN + j];   // coalesced rows
            int bad = is_inf_f(x);
            if (h == 0) cnt += 1 - bad;
            v[h] = bad ? 0.0f : x;
        }
        float4* dst = (float4*)(ad_out + (size_t)((b*NN+i)*NN + j)*16); // lane owns full 64B line
        dst[0] = make_float4(v[0], v[1], v[2], v[3]);
        dst[1] = make_float4(v[4], v[5], v[6], v[7]);
        dst[2] = make_float4(v[8], v[9], v[10], v[11]);
        dst[3] = make_float4(v[12], v[13], v[14], v[15]);
        const float cj0 = coords[(b*NN+j)*3+0];
        const float cj1 = coords[(b*NN+j)*3+1];
        const float cj2 = coords[(b*NN+j)*3+2];
        float e0, e1, e2;
        edge_vec(ci0, ci1, ci2, cj0, cj1, cj2, e0, e1, e2);
        ((float4*)ef_out)[(b*NN+i)*NN + j] = make_float4(1.0f, e0, e1, e2);
    }
    // attn_mask passthrough: same total element count as attn_disp
    {
        const float4* mi = (const float4*)mask;
        float4* mo = (float4*)mask_out;
        const int mbase = blk * 2048;
        #pragma unroll
        for (int r = 0; r < 8; r++) mo[mbase + r*256 + tid] = mi[mbase + r*256 + tid];
    }
    if (blk == 0) {
        for (int idx = tid; idx < 4*NN*3; idx += 256) coords_out[idx] = coords[idx];
    }
    // normalizer[b,i] = sqrt(#non-inf in attn_disp[b,0,i,:])
    #pragma unroll
    for (int off = 32; off >= 1; off >>= 1) cnt += __shfl_down(cnt, off);
    __shared__ int sred[4];
    if ((tid & 63) == 0) sred[tid >> 6] = cnt;
    __syncthreads();
    if (tid == 0) ws_norm[blk] = sqrtf((float)(sred[0]+sred[1]+sred[2]+sred[3]));
}

// K2: block = (b, j). For both nets: h = relu(ad@W1*0.25)*sqrt2 per edge (i,j),
// accumulate Hsum[c] and (e_k*h)[c] over all i. Also Se = sum_i e.
// Thread = (i_slot 0..31, c_slot 0..7); c_slot owns 4 hidden channels of both nets.
__global__ __launch_bounds__(256) void k_reduce(
    const float* __restrict__ ad, const float* __restrict__ coords,
    const float* __restrict__ wA, const float* __restrict__ wB,  // fc1_w1, fc2_w1 (16x32)
    float* __restrict__ ws)
{
    __shared__ float W0[512], W1[512];
    __shared__ float A[256*17];     // stride 17: conflict-free strided reads
    __shared__ float E[256*3];
    __shared__ float sred[12];
    const int blk = blockIdx.x;     // 2048 = B*N
    const int b = blk >> 9, j = blk & 511;
    const int tid = threadIdx.x;
    const int i_slot = tid & 31, c_slot = tid >> 5, c0 = c_slot * 4;
    W0[tid] = wA[tid]; W0[tid+256] = wA[tid+256];
    W1[tid] = wB[tid]; W1[tid+256] = wB[tid+256];
    const float cj0 = coords[(b*NN+j)*3+0];
    const float cj1 = coords[(b*NN+j)*3+1];
    const float cj2 = coords[(b*NN+j)*3+2];
    float se0 = 0.f, se1 = 0.f, se2 = 0.f;
    float acc[2][4][4];   // [net][c][ {1, e0, e1, e2} weighted sums ]
    #pragma unroll
    for (int n = 0; n < 2; n++)
        #pragma unroll
        for (int c = 0; c < 4; c++)
            #pragma unroll
            for (int w = 0; w < 4; w++) acc[n][c][w] = 0.f;

    for (int s = 0; s < 2; s++) {
        __syncthreads();
        const int i = s*256 + tid;
        const float4* src = (const float4*)(ad + (size_t)((b*NN+i)*NN + j)*16);
        float4 v0 = src[0], v1 = src[1], v2 = src[2], v3 = src[3];
        const int ab = tid*17;
        A[ab+ 0]=v0.x; A[ab+ 1]=v0.y; A[ab+ 2]=v0.z; A[ab+ 3]=v0.w;
        A[ab+ 4]=v1.x; A[ab+ 5]=v1.y; A[ab+ 6]=v1.z; A[ab+ 7]=v1.w;
        A[ab+ 8]=v2.x; A[ab+ 9]=v2.y; A[ab+10]=v2.z; A[ab+11]=v2.w;
        A[ab+12]=v3.x; A[ab+13]=v3.y; A[ab+14]=v3.z; A[ab+15]=v3.w;
        const float ci0 = coords[(b*NN+i)*3+0];
        const float ci1 = coords[(b*NN+i)*3+1];
        const float ci2 = coords[(b*NN+i)*3+2];
        float e0, e1, e2;
        edge_vec(ci0, ci1, ci2, cj0, cj1, cj2, e0, e1, e2);
        E[tid*3+0]=e0; E[tid*3+1]=e1; E[tid*3+2]=e2;
        se0 += e0; se1 += e1; se2 += e2;
        __syncthreads();
        for (int half = 0; half < 2; half++) {
            float a[4][16], ee[4][3];
            #pragma unroll
            for (int q = 0; q < 4; q++) {
                const int il = i_slot + 32*(half*4+q);
                const int ba = il*17;
                #pragma unroll
                for (int h = 0; h < 16; h++) a[q][h] = A[ba+h];
                ee[q][0]=E[il*3+0]; ee[q][1]=E[il*3+1]; ee[q][2]=E[il*3+2];
            }
            #pragma unroll
            for (int c = 0; c < 4; c++) {
                const int cc = c0 + c;
                #pragma unroll
                for (int net = 0; net < 2; net++) {
                    const float* __restrict__ Wn = net ? W1 : W0;
                    float t[4] = {0.f, 0.f, 0.f, 0.f};
                    #pragma unroll
                    for (int h = 0; h < 16; h++) {
                        const float w = Wn[h*32+cc];   // LDS broadcast
                        #pragma unroll
                        for (int q = 0; q < 4; q++) t[q] = fmaf(a[q][h], w, t[q]);
                    }
                    #pragma unroll
                    for (int q = 0; q < 4; q++) {
                        const float hq = fmaxf(t[q]*0.25f, 0.f) * 1.4142135623730951f;
                        acc[net][c][0] += hq;
                        acc[net][c][1] = fmaf(ee[q][0], hq, acc[net][c][1]);
                        acc[net][c][2] = fmaf(ee[q][1], hq, acc[net][c][2]);
                        acc[net][c][3] = fmaf(ee[q][2], hq, acc[net][c][3]);
                    }
                }
            }
        }
    }
    // reduce over the 32 i_slot lanes (block covers all i for its (b,j): no atomics)
    #pragma unroll
    for (int n = 0; n < 2; n++)
        #pragma unroll
        for (int c = 0; c < 4; c++)
            #pragma unroll
            for (int w = 0; w < 4; w++) {
                float v = acc[n][c][w];
                v += __shfl_xor(v, 1); v += __shfl_xor(v, 2); v += __shfl_xor(v, 4);
                v += __shfl_xor(v, 8); v += __shfl_xor(v, 16);
                acc[n][c][w] = v;
            }
    if (i_slot == 0) {
        float* accg = ws + 2048*4 + (size_t)blk*256;   // [net][w][c] rows of 32
        #pragma unroll
        for (int n = 0; n < 2; n++)
            #pragma unroll
            for (int w = 0; w < 4; w++)
                #pragma unroll
                for (int c = 0; c < 4; c++)
                    accg[(n*4+w)*32 + c0 + c] = acc[n][c][w];
    }
    // Se = sum_i e : full-wave reduce then cross-wave via LDS
    #pragma unroll
    for (int off = 1; off < 64; off <<= 1) {
        se0 += __shfl_xor(se0, off);
        se1 += __shfl_xor(se1, off);
        se2 += __shfl_xor(se2, off);
    }
    if ((tid & 63) == 0) {
        const int wv = tid >> 6;
        sred[wv*3+0] = se0; sred[wv*3+1] = se1; sred[wv*3+2] = se2;
    }
    __syncthreads();
    if (tid == 0) {
        float* seg = ws + 2048 + blk*3;
        seg[0] = sred[0]+sred[3]+sred[6]+sred[9];
        seg[1] = sred[1]+sred[4]+sred[7]+sred[10];
        seg[2] = sred[2]+sred[5]+sred[8]+sred[11];
    }
}

// K3: per (b,j): apply W2 of both nets to the reduced sums, then all the
// Wigner/gate algebra (odd-scalar channels of conv1 are identically 0 =>
// tanh gates vanish). One thread per node.
__global__ __launch_bounds__(256) void k_final(
    const float* __restrict__ ws,
    const float* __restrict__ w2a,   // fc1_w2 (32x14)
    const float* __restrict__ w2b,   // fc2_w2 (32x12)
    float* __restrict__ nf_out)
{
    const int bj = blockIdx.x*256 + threadIdx.x;   // 2048
    const float inv = 1.0f / ws[bj];
    const float s  = 512.0f * inv;                 // nf0 scalar = N/norm
    const float vv0 = ws[2048 + bj*3 + 0] * inv;
    const float vv1 = ws[2048 + bj*3 + 1] * inv;
    const float vv2 = ws[2048 + bj*3 + 2] * inv;
    const float* acc = ws + 2048*4 + (size_t)bj*256;
    const float ksc = 0.17677669529663687f;        // 1/sqrt(32) (fc second layer)
    // net1: S0 = plain sums @ W2, S1[k] = e_k-weighted sums @ W2
    float S0[14], S1[3][14];
    #pragma unroll
    for (int cc = 0; cc < 14; cc++) { S0[cc]=0.f; S1[0][cc]=0.f; S1[1][cc]=0.f; S1[2][cc]=0.f; }
    for (int c = 0; c < 32; c++) {
        const float p = acc[c], q0 = acc[32+c], q1 = acc[64+c], q2 = acc[96+c];
        #pragma unroll
        for (int cc = 0; cc < 14; cc++) {
            const float w = w2a[c*14+cc];
            S0[cc]    = fmaf(p,  w, S0[cc]);
            S1[0][cc] = fmaf(q0, w, S1[0][cc]);
            S1[1][cc] = fmaf(q1, w, S1[1][cc]);
            S1[2][cc] = fmaf(q2, w, S1[2][cc]);
        }
    }
    #pragma unroll
    for (int cc = 0; cc < 14; cc++) { S0[cc]*=ksc; S1[0][cc]*=ksc; S1[1][cc]*=ksc; S1[2][cc]*=ksc; }
    const float is2 = 0.7071067811865476f;   // 1/sqrt2
    const float is3 = 0.5773502691896258f;   // 1/sqrt3
    float x0[4];
    #pragma unroll
    for (int k = 0; k < 4; k++)
        x0[k] = inv*is2*( s*S0[k] + is3*(vv0*S1[0][4+k] + vv1*S1[1][4+k] + vv2*S1[2][4+k]) );
    const float vv[3] = {vv0, vv1, vv2};
    float x8[3];
    #pragma unroll
    for (int k = 0; k < 3; k++)
        x8[k] = inv*is2*( s*S1[k][8] + vv[k]*S0[10] );
    const float E12_0=S1[0][12], E12_1=S1[1][12], E12_2=S1[2][12];
    float x14[3];
    x14[0] = inv*is2*(vv1*E12_2 - vv2*E12_1);
    x14[1] = inv*is2*(vv2*E12_0 - vv0*E12_2);
    x14[2] = inv*is2*(vv0*E12_1 - vv1*E12_0);
    // gate
    const float a0 = fmaxf(x0[0],0.f), a1 = fmaxf(x0[1],0.f);
    const float g1 = fmaxf(x0[2],0.f), g3 = fmaxf(x0[3],0.f);
    const float p0=x8[0]*g1,  p1=x8[1]*g1,  p2=x8[2]*g1;
    const float q0_=x14[0]*g3, q1_=x14[1]*g3, q2_=x14[2]*g3;
    // net2
    float T0[12], T1[3][12];
    #pragma unroll
    for (int cc = 0; cc < 12; cc++){ T0[cc]=0.f; T1[0][cc]=0.f; T1[1][cc]=0.f; T1[2][cc]=0.f; }
    const float* acc2 = acc + 128;
    for (int c = 0; c < 32; c++) {
        const float p = acc2[c], r0 = acc2[32+c], r1 = acc2[64+c], r2 = acc2[96+c];
        #pragma unroll
        for (int cc = 0; cc < 12; cc++) {
            const float w = w2b[c*12+cc];
            T0[cc]    = fmaf(p,  w, T0[cc]);
            T1[0][cc] = fmaf(r0, w, T1[0][cc]);
            T1[1][cc] = fmaf(r1, w, T1[1][cc]);
            T1[2][cc] = fmaf(r2, w, T1[2][cc]);
        }
    }
    #pragma unroll
    for (int cc = 0; cc < 12; cc++){ T0[cc]*=ksc; T1[0][cc]*=ksc; T1[1][cc]*=ksc; T1[2][cc]*=ksc; }
    const float is6  = 0.4082482904638631f;    // 1/sqrt6
    const float is12 = 0.28867513459481287f;   // 1/sqrt12
    const float E0[3] = {T1[0][0], T1[1][0], T1[2][0]};
    const float E1[3] = {T1[0][1], T1[1][1], T1[2][1]};
    const float E4[3] = {T1[0][4], T1[1][4], T1[2][4]};
    const float E8[3] = {T1[0][8], T1[1][8], T1[2][8]};
    const float cq0 = q1_*E4[2] - q2_*E4[1];
    const float cq1 = q2_*E4[0] - q0_*E4[2];
    const float cq2 = q0_*E4[1] - q1_*E4[0];
    const float cp0 = p1*E8[2] - p2*E8[1];
    const float cp1 = p2*E8[0] - p0*E8[2];
    const float cp2 = p0*E8[1] - p1*E8[0];
    float o[6];
    o[0] = inv*( is6*(a0*E0[0] + a1*E1[0]) + is6*p0*T0[2] + is12*cq0 );
    o[1] = inv*( is6*(a0*E0[1] + a1*E1[1]) + is6*p1*T0[2] + is12*cq1 );
    o[2] = inv*( is6*(a0*E0[2] + a1*E1[2]) + is6*p2*T0[2] + is12*cq2 );
    o[3] = inv*( is12*cp0 + is6*q0_*T0[10] );
    o[4] = inv*( is12*cp1 + is6*q1_*T0[10] );
    o[5] = inv*( is12*cp2 + is6*q2_*T0[10] );
    #pragma unroll
    for (int k = 0; k < 6; k++) nf_out[bj*6+k] = o[k];
}

extern "C" void kernel_launch(void* const* d_in, const int* in_sizes, int n_in,
                              void* d_out, int out_size, void* d_ws, size_t ws_size,
                              hipStream_t stream) {
    const float* disp   = (const float*)d_in[0];   // (4,16,512,512)
    const float* mask   = (const float*)d_in[1];   // (64,512,512)
    const float* coords = (const float*)d_in[2];   // (4,512,3)
    const float* fc1w1  = (const float*)d_in[3];   // (16,32)
    const float* fc1w2  = (const float*)d_in[4];   // (32,14)
    const float* fc2w1  = (const float*)d_in[5];   // (16,32)
    const float* fc2w2  = (const float*)d_in[6];   // (32,12)
    float* out = (float*)d_out;
    float* ad_out     = out;                        // 16,777,216
    float* mask_out   = out + 16777216;             // 16,777,216
    float* coords_out = out + 33554432;             // 6,144
    float* nf_out     = coords_out + 6144;          // 12,288
    float* ef_out     = nf_out + 12288;             // 4,194,304
    float* ws = (float*)d_ws;   // norm[2048] | Se[2048*3] | acc[2048*256]  (~2.03 MiB)

    k_stage <<<2048, 256, 0, stream>>>(disp, mask, coords, ad_out, mask_out,
                                       coords_out, ef_out, ws);
    k_reduce<<<2048, 256, 0, stream>>>(ad_out, coords, fc1w1, fc2w1, ws);
    k_final <<<8,    256, 0, stream>>>(ws, fc1w2, fc2w2, nf_out);
}